// Round 5
// baseline (170.987 us; speedup 1.0000x reference)
//
#include <hip/hip_runtime.h>

// out[b*Lp + p, c, k] = x[b, c, p + k]
// B=128, C=4, L=2048, K=200, Lp=1849. 757 MB written -> write-bound.
//
// R2-R4 (tiled, per-block contiguous chunks) all plateau at ~150us while the
// harness memset hits 6.7 TB/s. Theory: ~700 concurrent 102KB-apart write
// streams destroy DRAM row-buffer locality; memset's grid-stride keeps one
// dense sliding window (row-hit streaks). This kernel copies the memset
// ordering exactly: grid-stride over output float4s, fully-resident grid
// (2048 blocks = 8/CU), one coalesced dwordx4 load per lane (x is 4MB,
// L2-resident), NONTEMPORAL stores so the 757MB write stream doesn't evict
// x from the 4MB/XCD L2 (reads re-stream 757MB from cache).

#define Q4_   47334400u          // total output float4s
#define T_    524288u            // grid(2048) * block(256) threads

typedef float f4u __attribute__((ext_vector_type(4), aligned(4)));

__device__ __forceinline__ const f4u* src_of(const float* __restrict__ x, unsigned int q)
{
    unsigned int k4   = q % 50u;
    unsigned int rem  = q / 50u;          // (b*1849 + p)*4 + c
    unsigned int c    = rem & 3u;
    unsigned int rem2 = rem >> 2u;        // b*1849 + p
    unsigned int p    = rem2 % 1849u;
    unsigned int b    = rem2 / 1849u;
    // float offset = (b*4+c)*2048 + p + 4*k4   (max = 1,048,575, in bounds)
    return reinterpret_cast<const f4u*>(x + (((b << 2u) + c) << 11u) + p + (k4 << 2u));
}

__global__ __launch_bounds__(256, 8) void unfold_stream(const float* __restrict__ x,
                                                        float* __restrict__ out)
{
    unsigned int tid = blockIdx.x * 256u + threadIdx.x;
    f4u* __restrict__ out4 = reinterpret_cast<f4u*>(out);

    unsigned int q = tid;

    // 22 batches of 4 (n = 0..87): all in range for every tid.
#pragma unroll 1
    for (int g = 0; g < 22; ++g) {
        unsigned int qa = q, qb = q + T_, qc = q + 2u * T_, qd = q + 3u * T_;
        f4u va = *src_of(x, qa);
        f4u vb = *src_of(x, qb);
        f4u vc = *src_of(x, qc);
        f4u vd = *src_of(x, qd);
        __builtin_nontemporal_store(va, out4 + qa);
        __builtin_nontemporal_store(vb, out4 + qb);
        __builtin_nontemporal_store(vc, out4 + qc);
        __builtin_nontemporal_store(vd, out4 + qd);
        q += 4u * T_;
    }
    // n = 88, 89: still in range for every tid.
    {
        f4u v = *src_of(x, q);
        __builtin_nontemporal_store(v, out4 + q);
        q += T_;
    }
    {
        f4u v = *src_of(x, q);
        __builtin_nontemporal_store(v, out4 + q);
        q += T_;
    }
    // n = 90: only tid < 148480.
    if (q < Q4_) {
        f4u v = *src_of(x, q);
        __builtin_nontemporal_store(v, out4 + q);
    }
}

extern "C" void kernel_launch(void* const* d_in, const int* in_sizes, int n_in,
                              void* d_out, int out_size, void* d_ws, size_t ws_size,
                              hipStream_t stream)
{
    const float* x = (const float*)d_in[0];
    float* out = (float*)d_out;

    unfold_stream<<<2048, 256, 0, stream>>>(x, out);
}

// Round 6
// 144.292 us; speedup vs baseline: 1.1850x; 1.1850x over previous
//
#include <hip/hip_runtime.h>

// out[b*Lp + p, c, k] = x[b, c, p + k]
// B=128, C=4, L=2048, K=200, Lp=1849. 757 MB written -> write-bound.
// R3 structure (4 phase-shifted LDS copies, one ds_read_b128 + one
// global_store_dwordx4 per output float4) + NEW: bijective XCD swizzle so
// each of the 8 XCDs writes ONE contiguous ~95MB region in dispatch order
// (write-side T1). Theory: per-XCD L2 writeback streams with dense address
// windows keep DRAM rows open at the shared memory controllers; default
// round-robin scatters each XCD's writes over all 757MB (row churn).

#define B_     128
#define C_     4
#define L_     2048
#define K_     200
#define LP_    1849
#define TP_    32              // p-rows per full tile
#define NT_    58              // 57 full tiles + 1 tail tile of 25 rows
#define TAIL_  25              // 1849 - 57*32
#define NSLOT_ 57              // float4 slots per (copy, channel)
#define NTILES_ (B_ * NT_)     // 7424 = 8 * 928
#define PERXCD_ (NTILES_ / 8)  // 928

__global__ __launch_bounds__(256) void unfold_swz(const float* __restrict__ x,
                                                  float* __restrict__ out)
{
    __shared__ float4 lds[16 * NSLOT_];   // 14.6 KB

    // Bijective XCD swizzle: block i runs on XCD (i&7) [round-robin dispatch].
    // Give XCD x the contiguous tile range [x*928, (x+1)*928) in launch order.
    unsigned int blk  = blockIdx.x;
    unsigned int tile = (blk & 7u) * PERXCD_ + (blk >> 3u);
    unsigned int b    = tile / NT_;
    unsigned int t    = tile - b * NT_;
    unsigned int p0   = t * TP_;
    unsigned int rows = (t == NT_ - 1) ? TAIL_ : TP_;

    // ---- Stage: task tau = (c, m). Load x[c][p0+4m .. +7], emit 4 shifted copies.
    unsigned int tau = threadIdx.x;
    if (tau < 4u * NSLOT_) {
        unsigned int c = tau / NSLOT_;
        unsigned int m = tau - c * NSLOT_;
        const float* row = x + (size_t)(b * 4u + c) * L_;
        unsigned int g = p0 + 4u * m;
        float v0x, v0y, v0z, v0w, v1x, v1y, v1z;
        if (g + 7u <= (unsigned)(L_ - 1)) {
            float4 v0 = *reinterpret_cast<const float4*>(row + g);
            float4 v1 = *reinterpret_cast<const float4*>(row + g + 4);
            v0x = v0.x; v0y = v0.y; v0z = v0.z; v0w = v0.w;
            v1x = v1.x; v1y = v1.y; v1z = v1.z;
        } else {
            v0x = row[min(g + 0u, 2047u)];
            v0y = row[min(g + 1u, 2047u)];
            v0z = row[min(g + 2u, 2047u)];
            v0w = row[min(g + 3u, 2047u)];
            v1x = row[min(g + 4u, 2047u)];
            v1y = row[min(g + 5u, 2047u)];
            v1z = row[min(g + 6u, 2047u)];
        }
        lds[(0u * 4u + c) * NSLOT_ + m] = make_float4(v0x, v0y, v0z, v0w);
        lds[(1u * 4u + c) * NSLOT_ + m] = make_float4(v0y, v0z, v0w, v1x);
        lds[(2u * 4u + c) * NSLOT_ + m] = make_float4(v0z, v0w, v1x, v1y);
        lds[(3u * 4u + c) * NSLOT_ + m] = make_float4(v0w, v1x, v1y, v1z);
    }
    __syncthreads();

    float4* out4 = reinterpret_cast<float4*>(out) + (size_t)(b * LP_ + p0) * 200u;
    unsigned int i = threadIdx.x;
    unsigned int p = i / 200u;
    unsigned int r = i - p * 200u;

    if (rows == TP_) {
#pragma unroll 5
        for (int n = 0; n < 25; ++n) {
            unsigned int c   = r / 50u;
            unsigned int k4  = r - c * 50u;
            unsigned int phi = p & 3u;
            unsigned int m   = (p >> 2u) + k4;
            out4[i] = lds[(phi * 4u + c) * NSLOT_ + m];
            i += 256u;
            unsigned int r2 = r + 56u;
            unsigned int w  = (r2 >= 200u) ? 1u : 0u;
            r = r2 - 200u * w;
            p += 1u + w;
        }
    } else {
        unsigned int n4 = rows * 200u;    // 5000
        for (; i < n4; i += 256u) {
            unsigned int c   = r / 50u;
            unsigned int k4  = r - c * 50u;
            unsigned int phi = p & 3u;
            unsigned int m   = (p >> 2u) + k4;
            out4[i] = lds[(phi * 4u + c) * NSLOT_ + m];
            unsigned int r2 = r + 56u;
            unsigned int w  = (r2 >= 200u) ? 1u : 0u;
            r = r2 - 200u * w;
            p += 1u + w;
        }
    }
}

extern "C" void kernel_launch(void* const* d_in, const int* in_sizes, int n_in,
                              void* d_out, int out_size, void* d_ws, size_t ws_size,
                              hipStream_t stream)
{
    const float* x = (const float*)d_in[0];
    float* out = (float*)d_out;

    unfold_swz<<<NTILES_, 256, 0, stream>>>(x, out);
}

// Round 8
// 143.868 us; speedup vs baseline: 1.1885x; 1.0029x over previous
//
#include <hip/hip_runtime.h>

// out[b*Lp + p, c, k] = x[b, c, p + k]
// B=128, C=4, L=2048, K=200, Lp=1849. 757 MB written -> write-bound.
// R6 structure (4 phase-shifted LDS copies -> one ds_read_b128 + one store
// per output float4, bijective XCD swizzle) + single new variable:
// NONTEMPORAL stores (ext_vector_type to satisfy the builtin's type check).

#define B_     128
#define C_     4
#define L_     2048
#define K_     200
#define LP_    1849
#define TP_    32              // p-rows per full tile
#define NT_    58              // 57 full tiles + 1 tail tile of 25 rows
#define TAIL_  25              // 1849 - 57*32
#define NSLOT_ 57              // float4 slots per (copy, channel)
#define NTILES_ (B_ * NT_)     // 7424 = 8 * 928
#define PERXCD_ (NTILES_ / 8)  // 928

typedef float f4 __attribute__((ext_vector_type(4)));

__global__ __launch_bounds__(256) void unfold_nt(const float* __restrict__ x,
                                                 float* __restrict__ out)
{
    __shared__ f4 lds[16 * NSLOT_];   // 14.6 KB

    unsigned int blk  = blockIdx.x;
    unsigned int tile = (blk & 7u) * PERXCD_ + (blk >> 3u);
    unsigned int b    = tile / NT_;
    unsigned int t    = tile - b * NT_;
    unsigned int p0   = t * TP_;
    unsigned int rows = (t == NT_ - 1) ? TAIL_ : TP_;

    // ---- Stage: task tau = (c, m). Load x[c][p0+4m .. +7], emit 4 shifted copies.
    unsigned int tau = threadIdx.x;
    if (tau < 4u * NSLOT_) {
        unsigned int c = tau / NSLOT_;
        unsigned int m = tau - c * NSLOT_;
        const float* row = x + (size_t)(b * 4u + c) * L_;
        unsigned int g = p0 + 4u * m;
        float v0x, v0y, v0z, v0w, v1x, v1y, v1z;
        if (g + 7u <= (unsigned)(L_ - 1)) {
            f4 v0 = *reinterpret_cast<const f4*>(row + g);
            f4 v1 = *reinterpret_cast<const f4*>(row + g + 4);
            v0x = v0.x; v0y = v0.y; v0z = v0.z; v0w = v0.w;
            v1x = v1.x; v1y = v1.y; v1z = v1.z;
        } else {
            v0x = row[min(g + 0u, 2047u)];
            v0y = row[min(g + 1u, 2047u)];
            v0z = row[min(g + 2u, 2047u)];
            v0w = row[min(g + 3u, 2047u)];
            v1x = row[min(g + 4u, 2047u)];
            v1y = row[min(g + 5u, 2047u)];
            v1z = row[min(g + 6u, 2047u)];
        }
        lds[(0u * 4u + c) * NSLOT_ + m] = (f4){v0x, v0y, v0z, v0w};
        lds[(1u * 4u + c) * NSLOT_ + m] = (f4){v0y, v0z, v0w, v1x};
        lds[(2u * 4u + c) * NSLOT_ + m] = (f4){v0z, v0w, v1x, v1y};
        lds[(3u * 4u + c) * NSLOT_ + m] = (f4){v0w, v1x, v1y, v1z};
    }
    __syncthreads();

    f4* out4 = reinterpret_cast<f4*>(out) + (size_t)(b * LP_ + p0) * 200u;
    unsigned int i = threadIdx.x;
    unsigned int p = i / 200u;
    unsigned int r = i - p * 200u;

    if (rows == TP_) {
#pragma unroll 5
        for (int n = 0; n < 25; ++n) {
            unsigned int c   = r / 50u;
            unsigned int k4  = r - c * 50u;
            unsigned int phi = p & 3u;
            unsigned int m   = (p >> 2u) + k4;
            f4 v = lds[(phi * 4u + c) * NSLOT_ + m];
            __builtin_nontemporal_store(v, out4 + i);
            i += 256u;
            unsigned int r2 = r + 56u;
            unsigned int w  = (r2 >= 200u) ? 1u : 0u;
            r = r2 - 200u * w;
            p += 1u + w;
        }
    } else {
        unsigned int n4 = rows * 200u;    // 5000
        for (; i < n4; i += 256u) {
            unsigned int c   = r / 50u;
            unsigned int k4  = r - c * 50u;
            unsigned int phi = p & 3u;
            unsigned int m   = (p >> 2u) + k4;
            f4 v = lds[(phi * 4u + c) * NSLOT_ + m];
            __builtin_nontemporal_store(v, out4 + i);
            unsigned int r2 = r + 56u;
            unsigned int w  = (r2 >= 200u) ? 1u : 0u;
            r = r2 - 200u * w;
            p += 1u + w;
        }
    }
}

extern "C" void kernel_launch(void* const* d_in, const int* in_sizes, int n_in,
                              void* d_out, int out_size, void* d_ws, size_t ws_size,
                              hipStream_t stream)
{
    const float* x = (const float*)d_in[0];
    float* out = (float*)d_out;

    unfold_nt<<<NTILES_, 256, 0, stream>>>(x, out);
}